// Round 3
// baseline (333.402 us; speedup 1.0000x reference)
//
#include <hip/hip_runtime.h>

#define KS   23      // 736/32 K-steps for GEMM1
#define FPAD 744     // feat LDS row stride (bf16)
#define BM   64      // edges per block
#define SMSZ (64*744*2)

typedef short bfrag8 __attribute__((ext_vector_type(8)));
typedef float f32x4 __attribute__((ext_vector_type(4)));

__device__ __forceinline__ unsigned short f2bf(float f) {
  union { float f; unsigned u; } v; v.f = f;
  unsigned r = v.u + 0x7fffu + ((v.u >> 16) & 1u);
  return (unsigned short)(r >> 16);
}
__device__ __forceinline__ unsigned pk2(float a, float b) {
  return (unsigned)f2bf(a) | ((unsigned)f2bf(b) << 16);
}

// ---- prep: weights -> fragment-major bf16 (contiguous 1KB per n16 x k32 MFMA tile) ----
__global__ void prep_weights(const float* __restrict__ cW1, const float* __restrict__ nW1,
                             const float* __restrict__ cW2, const float* __restrict__ nW2,
                             unsigned short* __restrict__ w1c, unsigned short* __restrict__ w1n,
                             unsigned short* __restrict__ w2c, unsigned short* __restrict__ w2n,
                             int* __restrict__ cnt) {
  int i = blockIdx.x * blockDim.x + threadIdx.x;
  if (i == 0) { cnt[0] = 0; cnt[1] = 0; }
  const int T0 = 12 * KS * 512, T1 = 8 * KS * 512, T2 = 8 * 6 * 512, T3 = 8 * 4 * 512;
  const int tot = T0 + T1 + T2 + T3;
  for (; i < tot; i += gridDim.x * blockDim.x) {
    int idx = i;
    const float* src; unsigned short* dst; int N, Kreal, KSm, rel;
    if (idx < T0)              { src = cW1; dst = w1c; N = 192; Kreal = 726; KSm = KS; rel = idx; }
    else if ((idx -= T0) < T1) { src = nW1; dst = w1n; N = 128; Kreal = 726; KSm = KS; rel = idx; }
    else if ((idx -= T1) < T2) { src = cW2; dst = w2c; N = 128; Kreal = 192; KSm = 6;  rel = idx; }
    else { idx -= T2;            src = nW2; dst = w2n; N = 128; Kreal = 128; KSm = 4;  rel = idx; }
    int blk = rel >> 9, within = rel & 511;
    int l = within >> 3, e = within & 7;
    int n16 = blk / KSm, k32 = blk - n16 * KSm;
    int n = n16 * 16 + (l & 15);
    int k = k32 * 32 + ((l >> 4) * 8) + e;
    dst[rel] = f2bf(k < Kreal ? src[(size_t)k * N + n] : 0.f);
  }
}

// ---- compaction: per-type packed records {src, dst, eid, packed_indices} ----
__global__ void compact_edges(const int* __restrict__ et,
                              const int* __restrict__ esrc, const int* __restrict__ edst,
                              const int* __restrict__ cts, const int* __restrict__ ctd,
                              const int* __restrict__ prs, const int* __restrict__ prd,
                              int* __restrict__ cnt, int4* __restrict__ r0, int4* __restrict__ r1,
                              float* __restrict__ out, int n) {
  int i = blockIdx.x * blockDim.x + threadIdx.x;
  for (; i < n; i += gridDim.x * blockDim.x) {
    int ty = et[i];
    if (ty == 0 || ty == 1) {
      int c1 = cts[i]; c1 = ((unsigned)c1 < 256u) ? c1 : 0;
      int c2 = ctd[i]; c2 = ((unsigned)c2 < 256u) ? c2 : 0;
      int p1 = prs[i]; p1 = ((unsigned)p1 < 64u)  ? p1 : 0;
      int p2 = prd[i]; p2 = ((unsigned)p2 < 64u)  ? p2 : 0;
      int4 rec; rec.x = esrc[i]; rec.y = edst[i]; rec.z = i;
      rec.w = c1 | (c2 << 8) | (p1 << 16) | (p2 << 22);
      if (ty == 0) r0[atomicAdd(&cnt[0], 1)] = rec;
      else         r1[atomicAdd(&cnt[1], 1)] = rec;
    } else {
      float4 z = make_float4(0.f, 0.f, 0.f, 0.f);
      float4* po = (float4*)(out + (size_t)i * 128);
      #pragma unroll
      for (int j = 0; j < 32; ++j) po[j] = z;
    }
  }
}

// ---- fused tile: feat -> GEMM1 -> LN/ReLU -> GEMM2 -> store.  512 thr, 8 waves (4m x 2n) ----
template <int CH>
__device__ __forceinline__ void mlp_tile(
    char* smraw, int* sEid, int tile, int c, int etv,
    const int4* __restrict__ rec,
    const float* __restrict__ h_nodes, const float* __restrict__ edge_scalars,
    const float* __restrict__ emb_et, const float* __restrict__ emb_ct, const float* __restrict__ emb_pr,
    const unsigned short* __restrict__ w1f, const unsigned short* __restrict__ w2f,
    const float* __restrict__ b1, const float* __restrict__ g,
    const float* __restrict__ beta, const float* __restrict__ b2,
    float* __restrict__ out)
{
  constexpr int NF  = CH / 32;   // GEMM1 n-frags per wave (6 or 4); also GEMM2 K-steps
  constexpr int CHP = CH + 8;
  unsigned short (*feat)[FPAD] = (unsigned short (*)[FPAD])smraw;
  unsigned short (*hb)[CHP]    = (unsigned short (*)[CHP])smraw;
  float (*red)[64][2] = (float (*)[64][2])(smraw + 90112);
  float (*murs)[2]    = (float (*)[2])(smraw + 94208);

  const int t    = threadIdx.x;
  const int lane = t & 63;
  const int wid  = t >> 6;
  const int mi   = wid & 3;
  const int ni   = wid >> 2;
  const int lrow = lane & 15;
  const int kq   = (lane >> 4) * 8;
  const int base = tile * BM;

  // early uniform loads (L2-resident, overlap with gathers)
  float b1r[NF], gr[NF], ber[NF];
  #pragma unroll
  for (int nf = 0; nf < NF; ++nf) {
    int ncol = ni * (CH / 2) + nf * 16 + lrow;
    b1r[nf] = b1[ncol]; gr[nf] = g[ncol]; ber[nf] = beta[ncol];
  }
  float b2r[4];
  #pragma unroll
  for (int nf2 = 0; nf2 < 4; ++nf2) b2r[nf2] = b2[ni * 64 + nf2 * 16 + lrow];

  // ---- Phase 1a: node gathers -> 5 derived segments (cols 0..639) ----
  {
    const int r = t >> 3, l8 = t & 7;
    const int idx = base + r;
    const bool valid = idx < c;
    int4 q = rec[valid ? idx : (c - 1)];
    if (l8 == 0) sEid[r] = valid ? q.z : -1;
    if (valid) {
      const float* bu = h_nodes + (size_t)q.x * 128;
      const float* bv = h_nodes + (size_t)q.y * 128;
      #pragma unroll
      for (int j = 0; j < 4; ++j) {
        const int d = (l8 + 8 * j) * 4;
        float4 uu = *(const float4*)(bu + d);
        float4 vv = *(const float4*)(bv + d);
        float ua[4] = {uu.x, uu.y, uu.z, uu.w};
        float va[4] = {vv.x, vv.y, vv.z, vv.w};
        uint2 s0 = make_uint2(pk2(ua[0], ua[1]), pk2(ua[2], ua[3]));
        uint2 s1 = make_uint2(pk2(va[0], va[1]), pk2(va[2], va[3]));
        uint2 s2 = make_uint2(pk2(ua[0] * va[0], ua[1] * va[1]), pk2(ua[2] * va[2], ua[3] * va[3]));
        uint2 s3 = make_uint2(pk2(fabsf(ua[0] - va[0]), fabsf(ua[1] - va[1])),
                              pk2(fabsf(ua[2] - va[2]), fabsf(ua[3] - va[3])));
        uint2 s4 = make_uint2(pk2(va[0] - ua[0], va[1] - ua[1]), pk2(va[2] - ua[2], va[3] - ua[3]));
        *(uint2*)&feat[r][0 * 128 + d] = s0;
        *(uint2*)&feat[r][1 * 128 + d] = s1;
        *(uint2*)&feat[r][2 * 128 + d] = s2;
        *(uint2*)&feat[r][3 * 128 + d] = s3;
        *(uint2*)&feat[r][4 * 128 + d] = s4;
      }
    } else {
      uint2 z = make_uint2(0u, 0u);
      #pragma unroll
      for (int j = 0; j < 4; ++j) {
        const int d = (l8 + 8 * j) * 4;
        #pragma unroll
        for (int s = 0; s < 5; ++s) *(uint2*)&feat[r][s * 128 + d] = z;
      }
    }
  }
  // ---- Phase 1b: embeddings + scalars (cols 640..735) ----
  {
    const int row = t & 63, eb = t >> 6;
    const int idx = base + row;
    const bool valid = idx < c;
    int4 q = rec[valid ? idx : (c - 1)];
    const int eid = q.z, pk = q.w;
    const int c1 = pk & 255, c2 = (pk >> 8) & 255, p1 = (pk >> 16) & 63, p2 = (pk >> 22) & 63;
    float vals[12];
    if (valid) {
      #pragma unroll
      for (int j = 0; j < 12; ++j) {
        int e = eb * 12 + j, tbl = e >> 4, off = e & 15;
        float v;
        if      (tbl == 0) v = emb_et[etv * 16 + off];
        else if (tbl == 1) v = emb_ct[c1 * 16 + off];
        else if (tbl == 2) v = emb_ct[c2 * 16 + off];
        else if (tbl == 3) v = emb_pr[p1 * 16 + off];
        else if (tbl == 4) v = emb_pr[p2 * 16 + off];
        else v = (off < 6) ? fminf(fmaxf(edge_scalars[(size_t)eid * 6 + off], -10.f), 10.f) : 0.f;
        vals[j] = v;
      }
    } else {
      #pragma unroll
      for (int j = 0; j < 12; ++j) vals[j] = 0.f;
    }
    uint2 w0 = make_uint2(pk2(vals[0], vals[1]), pk2(vals[2], vals[3]));
    uint2 w1_ = make_uint2(pk2(vals[4], vals[5]), pk2(vals[6], vals[7]));
    uint2 w2_ = make_uint2(pk2(vals[8], vals[9]), pk2(vals[10], vals[11]));
    *(uint2*)&feat[row][640 + eb * 12 + 0] = w0;
    *(uint2*)&feat[row][640 + eb * 12 + 4] = w1_;
    *(uint2*)&feat[row][640 + eb * 12 + 8] = w2_;
  }
  __syncthreads();

  // ---- Phase 2: GEMM1 with ring-3 B prefetch; 4 waves per n-group share B (L1 reuse) ----
  f32x4 acc1[NF];
  #pragma unroll
  for (int nf = 0; nf < NF; ++nf) acc1[nf] = 0;
  const unsigned short* wb = w1f + ((size_t)ni * NF * KS) * 512 + (size_t)lane * 8;
  bfrag8 br[3][NF];
  #pragma unroll
  for (int nf = 0; nf < NF; ++nf) {
    br[0][nf] = *(const bfrag8*)(wb + ((size_t)nf * KS + 0) * 512);
    br[1][nf] = *(const bfrag8*)(wb + ((size_t)nf * KS + 1) * 512);
  }
  #pragma unroll
  for (int k = 0; k < KS; ++k) {
    if (k + 2 < KS) {
      #pragma unroll
      for (int nf = 0; nf < NF; ++nf)
        br[(k + 2) % 3][nf] = *(const bfrag8*)(wb + ((size_t)nf * KS + (k + 2)) * 512);
    }
    bfrag8 a = *(const bfrag8*)&feat[mi * 16 + lrow][k * 32 + kq];
    #pragma unroll
    for (int nf = 0; nf < NF; ++nf)
      acc1[nf] = __builtin_amdgcn_mfma_f32_16x16x32_bf16(a, br[k % 3][nf], acc1[nf], 0, 0, 0);
  }
  __syncthreads();   // feat dead -> hb/red/murs overlay safe

  // ---- Phase 3: bias fold + in-register LN partials ----
  float sums[4], sqs[4];
  #pragma unroll
  for (int rg = 0; rg < 4; ++rg) {
    float s = 0.f, qd = 0.f;
    #pragma unroll
    for (int nf = 0; nf < NF; ++nf) {
      float v = acc1[nf][rg] + b1r[nf];
      acc1[nf][rg] = v;
      s += v; qd += v * v;
    }
    sums[rg] = s; sqs[rg] = qd;
  }
  #pragma unroll
  for (int d = 1; d < 16; d <<= 1) {
    #pragma unroll
    for (int rg = 0; rg < 4; ++rg) {
      sums[rg] += __shfl_xor(sums[rg], d);
      sqs[rg]  += __shfl_xor(sqs[rg], d);
    }
  }
  if (lrow == 0) {
    const int qr = lane >> 4;
    #pragma unroll
    for (int rg = 0; rg < 4; ++rg) {
      int row = mi * 16 + qr * 4 + rg;
      red[ni][row][0] = sums[rg];
      red[ni][row][1] = sqs[rg];
    }
  }
  __syncthreads();
  if (t < 64) {
    float ss = red[0][t][0] + red[1][t][0];
    float qq = red[0][t][1] + red[1][t][1];
    float m = ss * (1.f / CH);
    float va = fmaxf(qq * (1.f / CH) - m * m, 0.f);
    murs[t][0] = m;
    murs[t][1] = rsqrtf(va + 1e-5f);
  }
  __syncthreads();

  // ---- Phase 4: normalize + relu -> bf16 hb ----
  #pragma unroll
  for (int rg = 0; rg < 4; ++rg) {
    int row = mi * 16 + (lane >> 4) * 4 + rg;
    float m = murs[row][0], rv = murs[row][1];
    #pragma unroll
    for (int nf = 0; nf < NF; ++nf) {
      float v = (acc1[nf][rg] - m) * rv * gr[nf] + ber[nf];
      hb[row][ni * (CH / 2) + nf * 16 + lrow] = f2bf(fmaxf(v, 0.f));
    }
  }
  __syncthreads();

  // ---- Phase 5: GEMM2 (all B fragments loaded up-front; shared within n-group) ----
  f32x4 acc2[4];
  #pragma unroll
  for (int nf2 = 0; nf2 < 4; ++nf2) acc2[nf2] = 0;
  const unsigned short* wb2 = w2f + ((size_t)ni * 4 * NF) * 512 + (size_t)lane * 8;
  bfrag8 cr[NF][4];
  #pragma unroll
  for (int k2 = 0; k2 < NF; ++k2)
    #pragma unroll
    for (int nf2 = 0; nf2 < 4; ++nf2)
      cr[k2][nf2] = *(const bfrag8*)(wb2 + ((size_t)nf2 * NF + k2) * 512);
  #pragma unroll
  for (int k2 = 0; k2 < NF; ++k2) {
    bfrag8 a = *(const bfrag8*)&hb[mi * 16 + lrow][k2 * 32 + kq];
    #pragma unroll
    for (int nf2 = 0; nf2 < 4; ++nf2)
      acc2[nf2] = __builtin_amdgcn_mfma_f32_16x16x32_bf16(a, cr[k2][nf2], acc2[nf2], 0, 0, 0);
  }

  // ---- Phase 6: direct global stores ----
  #pragma unroll
  for (int rg = 0; rg < 4; ++rg) {
    int row = mi * 16 + (lane >> 4) * 4 + rg;
    int eid = sEid[row];
    if (eid >= 0) {
      float* po = out + (size_t)eid * 128 + ni * 64 + lrow;
      #pragma unroll
      for (int nf2 = 0; nf2 < 4; ++nf2)
        po[nf2 * 16] = acc2[nf2][rg] + b2r[nf2];
    }
  }
}

struct Args {
  const float *h_nodes, *edge_scalars;
  const float *emb_et, *emb_ct, *emb_pr;
  const unsigned short *w1c, *w2c;
  const float *cb1, *cg, *cbe, *cb2;
  const unsigned short *w1n, *w2n;
  const float *nb1, *ng, *nbe, *nb2;
  const int *cnt;
  const int4 *r0, *r1;
  float* out;
};

__global__ __launch_bounds__(512, 2) void edge_mlp_all(Args A) {
  __shared__ char smraw[SMSZ];
  __shared__ int sEid[64];
  const int c0 = A.cnt[0];
  const int nb0 = (c0 + BM - 1) / BM;
  const int b = blockIdx.x;
  if (b < nb0) {
    mlp_tile<192>(smraw, sEid, b, c0, 0, A.r0, A.h_nodes, A.edge_scalars,
                  A.emb_et, A.emb_ct, A.emb_pr, A.w1c, A.w2c,
                  A.cb1, A.cg, A.cbe, A.cb2, A.out);
  } else {
    const int c1 = A.cnt[1];
    const int t2 = b - nb0;
    if (t2 * BM < c1)
      mlp_tile<128>(smraw, sEid, t2, c1, 1, A.r1, A.h_nodes, A.edge_scalars,
                    A.emb_et, A.emb_ct, A.emb_pr, A.w1n, A.w2n,
                    A.nb1, A.ng, A.nbe, A.nb2, A.out);
  }
}

extern "C" void kernel_launch(void* const* d_in, const int* in_sizes, int n_in,
                              void* d_out, int out_size, void* d_ws, size_t ws_size,
                              hipStream_t stream) {
  (void)n_in; (void)out_size; (void)ws_size;
  const float* h_nodes      = (const float*)d_in[0];
  const float* edge_scalars = (const float*)d_in[1];
  const int*   edge_src     = (const int*)d_in[2];
  const int*   edge_dst     = (const int*)d_in[3];
  const int*   edge_type    = (const int*)d_in[4];
  const int*   ct_s         = (const int*)d_in[5];
  const int*   ct_d         = (const int*)d_in[6];
  const int*   pr_s         = (const int*)d_in[7];
  const int*   pr_d         = (const int*)d_in[8];
  const float* emb_et       = (const float*)d_in[9];
  const float* emb_ct       = (const float*)d_in[10];
  const float* emb_pr       = (const float*)d_in[11];
  const float* cW1 = (const float*)d_in[12];
  const float* cb1 = (const float*)d_in[13];
  const float* cg  = (const float*)d_in[14];
  const float* cbe = (const float*)d_in[15];
  const float* cW2 = (const float*)d_in[16];
  const float* cb2 = (const float*)d_in[17];
  const float* nW1 = (const float*)d_in[18];
  const float* nb1 = (const float*)d_in[19];
  const float* ng  = (const float*)d_in[20];
  const float* nbe = (const float*)d_in[21];
  const float* nW2 = (const float*)d_in[22];
  const float* nb2 = (const float*)d_in[23];
  const int n_edges = in_sizes[2];
  float* out = (float*)d_out;

  char* ws = (char*)d_ws;
  int* cnt = (int*)ws;
  int4* r0 = (int4*)(ws + 256);
  int4* r1 = r0 + n_edges;
  size_t woff = (256 + (size_t)2 * n_edges * sizeof(int4) + 255) & ~(size_t)255;
  unsigned short* w1c = (unsigned short*)(ws + woff);
  unsigned short* w1n = w1c + 12 * KS * 512;
  unsigned short* w2c = w1n + 8 * KS * 512;
  unsigned short* w2n = w2c + 8 * 6 * 512;

  prep_weights<<<1080, 256, 0, stream>>>(cW1, nW1, cW2, nW2, w1c, w1n, w2c, w2n, cnt);
  compact_edges<<<(n_edges + 255) / 256, 256, 0, stream>>>(edge_type, edge_src, edge_dst,
                                                           ct_s, ct_d, pr_s, pr_d,
                                                           cnt, r0, r1, out, n_edges);

  Args A;
  A.h_nodes = h_nodes; A.edge_scalars = edge_scalars;
  A.emb_et = emb_et; A.emb_ct = emb_ct; A.emb_pr = emb_pr;
  A.w1c = w1c; A.w2c = w2c; A.cb1 = cb1; A.cg = cg; A.cbe = cbe; A.cb2 = cb2;
  A.w1n = w1n; A.w2n = w2n; A.nb1 = nb1; A.ng = ng; A.nbe = nbe; A.nb2 = nb2;
  A.cnt = cnt; A.r0 = r0; A.r1 = r1; A.out = out;

  const int nbAll = (n_edges + BM - 1) / BM + 2;
  edge_mlp_all<<<nbAll, 512, 0, stream>>>(A);
}

// Round 5
// 213.128 us; speedup vs baseline: 1.5643x; 1.5643x over previous
//
#include <hip/hip_runtime.h>

#define KS   23      // 736/32 K-steps for GEMM1
#define FPAD 744     // feat LDS row stride (bf16)
#define BM   32      // edges per block

typedef short bfrag8 __attribute__((ext_vector_type(8)));
typedef float f32x4 __attribute__((ext_vector_type(4)));

__device__ __forceinline__ unsigned short f2bf(float f) {
  union { float f; unsigned u; } v; v.f = f;
  unsigned r = v.u + 0x7fffu + ((v.u >> 16) & 1u);
  return (unsigned short)(r >> 16);
}
__device__ __forceinline__ unsigned pk2(float a, float b) {
  return (unsigned)f2bf(a) | ((unsigned)f2bf(b) << 16);
}

// ---- prep: weights -> fragment-major bf16 (contiguous 1KB per n16 x k32 MFMA tile) ----
__global__ void prep_weights(const float* __restrict__ cW1, const float* __restrict__ nW1,
                             const float* __restrict__ cW2, const float* __restrict__ nW2,
                             unsigned short* __restrict__ w1c, unsigned short* __restrict__ w1n,
                             unsigned short* __restrict__ w2c, unsigned short* __restrict__ w2n,
                             int* __restrict__ cnt) {
  int i = blockIdx.x * blockDim.x + threadIdx.x;
  if (i == 0) { cnt[0] = 0; cnt[1] = 0; }
  const int T0 = 12 * KS * 512, T1 = 8 * KS * 512, T2 = 8 * 6 * 512, T3 = 8 * 4 * 512;
  const int tot = T0 + T1 + T2 + T3;
  for (; i < tot; i += gridDim.x * blockDim.x) {
    int idx = i;
    const float* src; unsigned short* dst; int N, Kreal, KSm, rel;
    if (idx < T0)              { src = cW1; dst = w1c; N = 192; Kreal = 726; KSm = KS; rel = idx; }
    else if ((idx -= T0) < T1) { src = nW1; dst = w1n; N = 128; Kreal = 726; KSm = KS; rel = idx; }
    else if ((idx -= T1) < T2) { src = cW2; dst = w2c; N = 128; Kreal = 192; KSm = 6;  rel = idx; }
    else { idx -= T2;            src = nW2; dst = w2n; N = 128; Kreal = 128; KSm = 4;  rel = idx; }
    int blk = rel >> 9, within = rel & 511;
    int l = within >> 3, e = within & 7;
    int n16 = blk / KSm, k32 = blk - n16 * KSm;
    int n = n16 * 16 + (l & 15);
    int k = k32 * 32 + ((l >> 4) * 8) + e;
    dst[rel] = f2bf(k < Kreal ? src[(size_t)k * N + n] : 0.f);
  }
}

// ---- compaction: per-type packed records {src, dst, eid, packed_indices} ----
__global__ void compact_edges(const int* __restrict__ et,
                              const int* __restrict__ esrc, const int* __restrict__ edst,
                              const int* __restrict__ cts, const int* __restrict__ ctd,
                              const int* __restrict__ prs, const int* __restrict__ prd,
                              int* __restrict__ cnt, int4* __restrict__ r0, int4* __restrict__ r1,
                              float* __restrict__ out, int n) {
  int i = blockIdx.x * blockDim.x + threadIdx.x;
  for (; i < n; i += gridDim.x * blockDim.x) {
    int ty = et[i];
    if (ty == 0 || ty == 1) {
      int c1 = cts[i]; c1 = ((unsigned)c1 < 256u) ? c1 : 0;
      int c2 = ctd[i]; c2 = ((unsigned)c2 < 256u) ? c2 : 0;
      int p1 = prs[i]; p1 = ((unsigned)p1 < 64u)  ? p1 : 0;
      int p2 = prd[i]; p2 = ((unsigned)p2 < 64u)  ? p2 : 0;
      int4 rec; rec.x = esrc[i]; rec.y = edst[i]; rec.z = i;
      rec.w = c1 | (c2 << 8) | (p1 << 16) | (p2 << 22);
      if (ty == 0) r0[atomicAdd(&cnt[0], 1)] = rec;
      else         r1[atomicAdd(&cnt[1], 1)] = rec;
    } else {
      float4 z = make_float4(0.f, 0.f, 0.f, 0.f);
      float4* po = (float4*)(out + (size_t)i * 128);
      #pragma unroll
      for (int j = 0; j < 32; ++j) po[j] = z;
    }
  }
}

// ---- fused tile: 256 thr, 4 waves; each wave owns an n-slice, all 32 rows ----
template <int CH>
__device__ __forceinline__ void mlp_tile(
    char* smraw, int* sEid, int tile, int c, int etv,
    const int4* __restrict__ rec,
    const float* __restrict__ h_nodes, const float* __restrict__ edge_scalars,
    const float* __restrict__ emb_et, const float* __restrict__ emb_ct, const float* __restrict__ emb_pr,
    const unsigned short* __restrict__ w1f, const unsigned short* __restrict__ w2f,
    const float* __restrict__ b1, const float* __restrict__ g,
    const float* __restrict__ beta, const float* __restrict__ b2,
    float* __restrict__ out)
{
  constexpr int NF  = CH / 64;   // GEMM1 n-frags per wave (3 or 2)
  constexpr int KS2 = CH / 32;   // GEMM2 K-steps (6 or 4)
  constexpr int CHP = CH + 8;
  unsigned short (*feat)[FPAD] = (unsigned short (*)[FPAD])smraw;
  unsigned short (*hb)[CHP]    = (unsigned short (*)[CHP])smraw;
  float (*red)[BM][2] = (float (*)[BM][2])(smraw + BM * CHP * 2);
  float (*murs)[2]    = (float (*)[2])(smraw + BM * CHP * 2 + 4 * BM * 2 * 4);

  const int t    = threadIdx.x;
  const int lane = t & 63;
  const int wid  = t >> 6;
  const int lrow = lane & 15;
  const int kq   = (lane >> 4) * 8;
  const int base = tile * BM;
  const int r    = t >> 3;       // 0..31 row
  const int l8   = t & 7;        // 8 threads per row

  // ---- uniform per-lane params (independent loads, issue first) ----
  float b1r[NF], gr[NF], ber[NF];
  #pragma unroll
  for (int nf = 0; nf < NF; ++nf) {
    int n = wid * (CH / 4) + nf * 16 + lrow;
    b1r[nf] = b1[n]; gr[nf] = g[n]; ber[nf] = beta[n];
  }
  float b2r[2];
  #pragma unroll
  for (int nf2 = 0; nf2 < 2; ++nf2) b2r[nf2] = b2[wid * 32 + nf2 * 16 + lrow];

  // ---- record (uniform control flow; invalid rows read a safe record) ----
  const int idx  = base + r;
  const bool valid = idx < c;
  int4 q = rec[valid ? idx : (c - 1)];
  if (l8 == 0) sEid[r] = valid ? q.z : -1;

  // ---- Phase 1: batched loads into registers (8 u/v float4 + emb segment) ----
  const float* bu = h_nodes + (size_t)q.x * 128;
  const float* bv = h_nodes + (size_t)q.y * 128;
  float4 ub[4], vb[4];
  #pragma unroll
  for (int j = 0; j < 4; ++j) {
    const int d = (l8 + 8 * j) * 4;
    ub[j] = *(const float4*)(bu + d);
    vb[j] = *(const float4*)(bv + d);
  }
  // emb segment: thread (row, l8) handles 16 cols starting at 640+16*l8
  const int pk = q.w;
  const int c1 = pk & 255, c2 = (pk >> 8) & 255, p1 = (pk >> 16) & 63, p2 = (pk >> 22) & 63;
  const float* tp = (l8 == 0) ? emb_et + etv * 16
                  : (l8 == 1) ? emb_ct + c1 * 16
                  : (l8 == 2) ? emb_ct + c2 * 16
                  : (l8 == 3) ? emb_pr + p1 * 16
                  :             emb_pr + p2 * 16;
  float4 e4[4];
  if (l8 < 5) {
    #pragma unroll
    for (int j = 0; j < 4; ++j) e4[j] = ((const float4*)tp)[j];
  }
  float2 sc2[3];
  if (l8 == 5) {
    const float2* sp = (const float2*)(edge_scalars + (size_t)q.z * 6);
    #pragma unroll
    for (int j = 0; j < 3; ++j) sc2[j] = sp[j];
  }

  // ---- convert + LDS writes ----
  if (valid) {
    #pragma unroll
    for (int j = 0; j < 4; ++j) {
      const int d = (l8 + 8 * j) * 4;
      float ua[4] = {ub[j].x, ub[j].y, ub[j].z, ub[j].w};
      float va[4] = {vb[j].x, vb[j].y, vb[j].z, vb[j].w};
      uint2 s0 = make_uint2(pk2(ua[0], ua[1]), pk2(ua[2], ua[3]));
      uint2 s1 = make_uint2(pk2(va[0], va[1]), pk2(va[2], va[3]));
      uint2 s2 = make_uint2(pk2(ua[0] * va[0], ua[1] * va[1]), pk2(ua[2] * va[2], ua[3] * va[3]));
      uint2 s3 = make_uint2(pk2(fabsf(ua[0] - va[0]), fabsf(ua[1] - va[1])),
                            pk2(fabsf(ua[2] - va[2]), fabsf(ua[3] - va[3])));
      uint2 s4 = make_uint2(pk2(va[0] - ua[0], va[1] - ua[1]), pk2(va[2] - ua[2], va[3] - ua[3]));
      *(uint2*)&feat[r][0 * 128 + d] = s0;
      *(uint2*)&feat[r][1 * 128 + d] = s1;
      *(uint2*)&feat[r][2 * 128 + d] = s2;
      *(uint2*)&feat[r][3 * 128 + d] = s3;
      *(uint2*)&feat[r][4 * 128 + d] = s4;
    }
  } else {
    uint2 z = make_uint2(0u, 0u);
    #pragma unroll
    for (int j = 0; j < 4; ++j) {
      const int d = (l8 + 8 * j) * 4;
      #pragma unroll
      for (int s = 0; s < 5; ++s) *(uint2*)&feat[r][s * 128 + d] = z;
    }
  }
  if (l8 < 5) {
    float va[16];
    #pragma unroll
    for (int j = 0; j < 4; ++j) {
      va[4 * j + 0] = e4[j].x; va[4 * j + 1] = e4[j].y;
      va[4 * j + 2] = e4[j].z; va[4 * j + 3] = e4[j].w;
    }
    if (!valid) {
      #pragma unroll
      for (int j = 0; j < 16; ++j) va[j] = 0.f;
    }
    uint4 w0 = make_uint4(pk2(va[0], va[1]), pk2(va[2], va[3]), pk2(va[4], va[5]), pk2(va[6], va[7]));
    uint4 w1_ = make_uint4(pk2(va[8], va[9]), pk2(va[10], va[11]), pk2(va[12], va[13]), pk2(va[14], va[15]));
    *(uint4*)&feat[r][640 + l8 * 16 + 0] = w0;
    *(uint4*)&feat[r][640 + l8 * 16 + 8] = w1_;
  } else if (l8 == 5) {
    float sv[6] = {sc2[0].x, sc2[0].y, sc2[1].x, sc2[1].y, sc2[2].x, sc2[2].y};
    #pragma unroll
    for (int j = 0; j < 6; ++j)
      sv[j] = valid ? fminf(fmaxf(sv[j], -10.f), 10.f) : 0.f;
    uint4 w0 = make_uint4(pk2(sv[0], sv[1]), pk2(sv[2], sv[3]), pk2(sv[4], sv[5]), 0u);
    uint4 w1_ = make_uint4(0u, 0u, 0u, 0u);
    *(uint4*)&feat[r][720 + 0] = w0;
    *(uint4*)&feat[r][720 + 8] = w1_;
  }
  __syncthreads();

  // ---- Phase 2: GEMM1 with ring-3 B prefetch ----
  f32x4 acc1[2][NF];
  #pragma unroll
  for (int mf = 0; mf < 2; ++mf)
    #pragma unroll
    for (int nf = 0; nf < NF; ++nf) acc1[mf][nf] = 0;
  const unsigned short* wb = w1f + ((size_t)wid * NF * KS) * 512 + (size_t)lane * 8;
  bfrag8 br[3][NF];
  #pragma unroll
  for (int nf = 0; nf < NF; ++nf) {
    br[0][nf] = *(const bfrag8*)(wb + ((size_t)nf * KS + 0) * 512);
    br[1][nf] = *(const bfrag8*)(wb + ((size_t)nf * KS + 1) * 512);
  }
  #pragma unroll
  for (int k = 0; k < KS; ++k) {
    if (k + 2 < KS) {
      #pragma unroll
      for (int nf = 0; nf < NF; ++nf)
        br[(k + 2) % 3][nf] = *(const bfrag8*)(wb + ((size_t)nf * KS + (k + 2)) * 512);
    }
    bfrag8 a0 = *(const bfrag8*)&feat[lrow][k * 32 + kq];
    bfrag8 a1 = *(const bfrag8*)&feat[16 + lrow][k * 32 + kq];
    #pragma unroll
    for (int nf = 0; nf < NF; ++nf) {
      acc1[0][nf] = __builtin_amdgcn_mfma_f32_16x16x32_bf16(a0, br[k % 3][nf], acc1[0][nf], 0, 0, 0);
      acc1[1][nf] = __builtin_amdgcn_mfma_f32_16x16x32_bf16(a1, br[k % 3][nf], acc1[1][nf], 0, 0, 0);
    }
  }

  // ---- issue GEMM2 B loads now; latency hides under LN ----
  bfrag8 cr[KS2][2];
  const unsigned short* wb2 = w2f + (size_t)lane * 8;
  #pragma unroll
  for (int k2 = 0; k2 < KS2; ++k2)
    #pragma unroll
    for (int nf2 = 0; nf2 < 2; ++nf2)
      cr[k2][nf2] = *(const bfrag8*)(wb2 + ((size_t)(2 * wid + nf2) * KS2 + k2) * 512);

  __syncthreads();   // feat dead -> hb/red/murs overlay safe

  // ---- Phase 3: bias fold + in-register LN partials ----
  float sums[2][4], sqs[2][4];
  #pragma unroll
  for (int mf = 0; mf < 2; ++mf)
    #pragma unroll
    for (int rg = 0; rg < 4; ++rg) {
      float s = 0.f, qd = 0.f;
      #pragma unroll
      for (int nf = 0; nf < NF; ++nf) {
        float v = acc1[mf][nf][rg] + b1r[nf];
        acc1[mf][nf][rg] = v;
        s += v; qd += v * v;
      }
      sums[mf][rg] = s; sqs[mf][rg] = qd;
    }
  #pragma unroll
  for (int d = 1; d < 16; d <<= 1) {
    #pragma unroll
    for (int mf = 0; mf < 2; ++mf)
      #pragma unroll
      for (int rg = 0; rg < 4; ++rg) {
        sums[mf][rg] += __shfl_xor(sums[mf][rg], d);
        sqs[mf][rg]  += __shfl_xor(sqs[mf][rg], d);
      }
  }
  if (lrow == 0) {
    const int qr = lane >> 4;
    #pragma unroll
    for (int mf = 0; mf < 2; ++mf)
      #pragma unroll
      for (int rg = 0; rg < 4; ++rg) {
        int row = mf * 16 + qr * 4 + rg;
        red[wid][row][0] = sums[mf][rg];
        red[wid][row][1] = sqs[mf][rg];
      }
  }
  __syncthreads();
  if (t < BM) {
    float ss = red[0][t][0] + red[1][t][0] + red[2][t][0] + red[3][t][0];
    float qq = red[0][t][1] + red[1][t][1] + red[2][t][1] + red[3][t][1];
    float m = ss * (1.f / CH);
    float va = fmaxf(qq * (1.f / CH) - m * m, 0.f);
    murs[t][0] = m;
    murs[t][1] = rsqrtf(va + 1e-5f);
  }
  __syncthreads();

  // ---- Phase 4: normalize + relu -> bf16 hb ----
  #pragma unroll
  for (int mf = 0; mf < 2; ++mf)
    #pragma unroll
    for (int rg = 0; rg < 4; ++rg) {
      int row = mf * 16 + (lane >> 4) * 4 + rg;
      float m = murs[row][0], rv = murs[row][1];
      #pragma unroll
      for (int nf = 0; nf < NF; ++nf) {
        float v = (acc1[mf][nf][rg] - m) * rv * gr[nf] + ber[nf];
        hb[row][wid * (CH / 4) + nf * 16 + lrow] = f2bf(fmaxf(v, 0.f));
      }
    }
  __syncthreads();

  // ---- Phase 5: GEMM2 (B already in registers) ----
  f32x4 acc2[2][2];
  #pragma unroll
  for (int mf = 0; mf < 2; ++mf) { acc2[mf][0] = 0; acc2[mf][1] = 0; }
  #pragma unroll
  for (int k2 = 0; k2 < KS2; ++k2) {
    bfrag8 a0 = *(const bfrag8*)&hb[lrow][k2 * 32 + kq];
    bfrag8 a1 = *(const bfrag8*)&hb[16 + lrow][k2 * 32 + kq];
    #pragma unroll
    for (int nf2 = 0; nf2 < 2; ++nf2) {
      acc2[0][nf2] = __builtin_amdgcn_mfma_f32_16x16x32_bf16(a0, cr[k2][nf2], acc2[0][nf2], 0, 0, 0);
      acc2[1][nf2] = __builtin_amdgcn_mfma_f32_16x16x32_bf16(a1, cr[k2][nf2], acc2[1][nf2], 0, 0, 0);
    }
  }

  // ---- Phase 6: direct global stores ----
  #pragma unroll
  for (int mf = 0; mf < 2; ++mf)
    #pragma unroll
    for (int rg = 0; rg < 4; ++rg) {
      int row = mf * 16 + (lane >> 4) * 4 + rg;
      int eid = sEid[row];
      if (eid >= 0) {
        float* po = out + (size_t)eid * 128 + wid * 32 + lrow;
        #pragma unroll
        for (int nf2 = 0; nf2 < 2; ++nf2)
          po[nf2 * 16] = acc2[mf][nf2][rg] + b2r[nf2];
      }
    }
}

struct Args {
  const float *h_nodes, *edge_scalars;
  const float *emb_et, *emb_ct, *emb_pr;
  const unsigned short *w1c, *w2c;
  const float *cb1, *cg, *cbe, *cb2;
  const unsigned short *w1n, *w2n;
  const float *nb1, *ng, *nbe, *nb2;
  const int *cnt;
  const int4 *r0, *r1;
  float* out;
};

__global__ __launch_bounds__(256, 4) void edge_mlp_all(Args A) {
  __shared__ alignas(16) char smraw[BM * FPAD * 2];
  __shared__ int sEid[BM];
  const int c0 = A.cnt[0];
  const int nb0 = (c0 + BM - 1) / BM;
  const int b = blockIdx.x;
  if (b < nb0) {
    mlp_tile<192>(smraw, sEid, b, c0, 0, A.r0, A.h_nodes, A.edge_scalars,
                  A.emb_et, A.emb_ct, A.emb_pr, A.w1c, A.w2c,
                  A.cb1, A.cg, A.cbe, A.cb2, A.out);
  } else {
    const int c1 = A.cnt[1];
    const int t2 = b - nb0;
    if (t2 * BM < c1)
      mlp_tile<128>(smraw, sEid, t2, c1, 1, A.r1, A.h_nodes, A.edge_scalars,
                    A.emb_et, A.emb_ct, A.emb_pr, A.w1n, A.w2n,
                    A.nb1, A.ng, A.nbe, A.nb2, A.out);
  }
}

extern "C" void kernel_launch(void* const* d_in, const int* in_sizes, int n_in,
                              void* d_out, int out_size, void* d_ws, size_t ws_size,
                              hipStream_t stream) {
  (void)n_in; (void)out_size; (void)ws_size;
  const float* h_nodes      = (const float*)d_in[0];
  const float* edge_scalars = (const float*)d_in[1];
  const int*   edge_src     = (const int*)d_in[2];
  const int*   edge_dst     = (const int*)d_in[3];
  const int*   edge_type    = (const int*)d_in[4];
  const int*   ct_s         = (const int*)d_in[5];
  const int*   ct_d         = (const int*)d_in[6];
  const int*   pr_s         = (const int*)d_in[7];
  const int*   pr_d         = (const int*)d_in[8];
  const float* emb_et       = (const float*)d_in[9];
  const float* emb_ct       = (const float*)d_in[10];
  const float* emb_pr       = (const float*)d_in[11];
  const float* cW1 = (const float*)d_in[12];
  const float* cb1 = (const float*)d_in[13];
  const float* cg  = (const float*)d_in[14];
  const float* cbe = (const float*)d_in[15];
  const float* cW2 = (const float*)d_in[16];
  const float* cb2 = (const float*)d_in[17];
  const float* nW1 = (const float*)d_in[18];
  const float* nb1 = (const float*)d_in[19];
  const float* ng  = (const float*)d_in[20];
  const float* nbe = (const float*)d_in[21];
  const float* nW2 = (const float*)d_in[22];
  const float* nb2 = (const float*)d_in[23];
  const int n_edges = in_sizes[2];
  float* out = (float*)d_out;

  char* ws = (char*)d_ws;
  int* cnt = (int*)ws;
  int4* r0 = (int4*)(ws + 256);
  int4* r1 = r0 + n_edges;
  size_t woff = (256 + (size_t)2 * n_edges * sizeof(int4) + 255) & ~(size_t)255;
  unsigned short* w1c = (unsigned short*)(ws + woff);
  unsigned short* w1n = w1c + 12 * KS * 512;
  unsigned short* w2c = w1n + 8 * KS * 512;
  unsigned short* w2n = w2c + 8 * 6 * 512;

  prep_weights<<<1080, 256, 0, stream>>>(cW1, nW1, cW2, nW2, w1c, w1n, w2c, w2n, cnt);
  compact_edges<<<(n_edges + 255) / 256, 256, 0, stream>>>(edge_type, edge_src, edge_dst,
                                                           ct_s, ct_d, pr_s, pr_d,
                                                           cnt, r0, r1, out, n_edges);

  Args A;
  A.h_nodes = h_nodes; A.edge_scalars = edge_scalars;
  A.emb_et = emb_et; A.emb_ct = emb_ct; A.emb_pr = emb_pr;
  A.w1c = w1c; A.w2c = w2c; A.cb1 = cb1; A.cg = cg; A.cbe = cbe; A.cb2 = cb2;
  A.w1n = w1n; A.w2n = w2n; A.nb1 = nb1; A.ng = ng; A.nbe = nbe; A.nb2 = nb2;
  A.cnt = cnt; A.r0 = r0; A.r1 = r1; A.out = out;

  const int nbAll = (n_edges + BM - 1) / BM + 2;
  edge_mlp_all<<<nbAll, 256, 0, stream>>>(A);
}